// Round 1
// baseline (388.314 us; speedup 1.0000x reference)
//
#include <hip/hip_runtime.h>

// Problem constants (B,S,D_IN,D_HID,D_OUT) = (8,4096,512,1024,512)
#define B_    8
#define S_    4096
#define DIN   512
#define DHID  1024
#define DOUT  512
#define M_    (B_*S_)          // 32768
#define NCAT  (DHID + DOUT)    // 1536
#define CHUNK 128
#define NCH   (S_/CHUNK)       // 32

typedef __bf16 bf16x8 __attribute__((ext_vector_type(8)));
typedef float  floatx4 __attribute__((ext_vector_type(4)));

__device__ __forceinline__ unsigned short f2bf(float f) {
  unsigned u = __builtin_bit_cast(unsigned, f);
  u = (u + 0x7FFFu + ((u >> 16) & 1u)) >> 16;   // RNE
  return (unsigned short)u;
}
__device__ __forceinline__ float bf2f(unsigned short h) {
  unsigned u = ((unsigned)h) << 16;
  return __builtin_bit_cast(float, u);
}

// ---------- prep kernels ----------
__global__ void prep_as(const float* __restrict__ logit, float* __restrict__ a_s) {
  int d = blockIdx.x * 256 + threadIdx.x;
  if (d < DHID) {
    float a = 1.f / (1.f + expf(-logit[d]));
    a_s[d] = a;
    a_s[DHID + d] = sqrtf(fmaxf(1.f - a * a, 0.f));
  }
}

// x fp32 -> bf16, 8 elems/thread
__global__ void prep_x(const float* __restrict__ x, unsigned short* __restrict__ xb) {
  size_t i = (size_t)blockIdx.x * 256 + threadIdx.x;
  const float4* p = (const float4*)x;
  float4 v0 = p[i * 2];
  float4 v1 = p[i * 2 + 1];
  uint4 o;
  o.x = (unsigned)f2bf(v0.x) | ((unsigned)f2bf(v0.y) << 16);
  o.y = (unsigned)f2bf(v0.z) | ((unsigned)f2bf(v0.w) << 16);
  o.z = (unsigned)f2bf(v1.x) | ((unsigned)f2bf(v1.y) << 16);
  o.w = (unsigned)f2bf(v1.z) | ((unsigned)f2bf(v1.w) << 16);
  *(uint4*)&xb[i * 8] = o;
}

// Wcat^T bf16: rows n in [0,1536), cols k in [0,512). n<1024 -> W_in[:,n], else W_dx[:,n-1024]
__global__ void prep_wcat(const float* __restrict__ Win, const float* __restrict__ Wdx,
                          unsigned short* __restrict__ wcat) {
  int idx = blockIdx.x * 256 + threadIdx.x;   // n*512 + k
  int n = idx >> 9, k = idx & 511;
  float v = (n < DHID) ? Win[(size_t)k * DHID + n] : Wdx[(size_t)k * DOUT + (n - DHID)];
  wcat[idx] = f2bf(v);
}

// Wout^T bf16: rows n in [0,512), cols k in [0,1024)
__global__ void prep_wout(const float* __restrict__ Wout, unsigned short* __restrict__ wt) {
  int idx = blockIdx.x * 256 + threadIdx.x;   // n*1024 + k
  int n = idx >> 10, k = idx & 1023;
  wt[idx] = f2bf(Wout[(size_t)k * DOUT + n]);
}

// ---------- GEMM (128x128 tile, 4 waves of 64x64, mfma 16x16x32 bf16) ----------
// MODE 0: C = A(M x K=512) * Wcat^T; epilogue: n<1024 -> u=(c+b_in[n])*s[n] bf16;
//                                              n>=1024 -> dx=(c+b_dx) bf16
// MODE 1: C = H(M x K=1024) * Wout^T; epilogue: out=(c+b_out+dx)*0.5 fp32
template <int K, int MODE>
__global__ __launch_bounds__(256) void gemm_bt(
    const unsigned short* __restrict__ A,    // M x K bf16 row-major
    const unsigned short* __restrict__ Bt,   // N x K bf16 row-major
    const float* __restrict__ a_s,           // [a | s]
    const float* __restrict__ bias0,         // b_in (MODE0) / b_out (MODE1)
    const float* __restrict__ bias1,         // b_dx (MODE0)
    unsigned short* __restrict__ u_out,      // MODE0
    unsigned short* __restrict__ dx_buf,     // MODE0 out / MODE1 in
    float* __restrict__ out)                 // MODE1
{
  __shared__ __align__(16) unsigned short lA[128 * 64];
  __shared__ __align__(16) unsigned short lB[128 * 64];

  const int tid = threadIdx.x;
  const int m0 = blockIdx.x * 128, n0 = blockIdx.y * 128;
  const int wid = tid >> 6, lane = tid & 63;
  const int wm = (wid >> 1) * 64, wn = (wid & 1) * 64;
  const int r16 = lane & 15, quad = lane >> 4;

  const int srow = tid >> 3;        // 0..31
  const int scol = (tid & 7) * 8;   // 0..56

  floatx4 acc[4][4] = {};

  for (int k0 = 0; k0 < K; k0 += 64) {
#pragma unroll
    for (int p = 0; p < 4; ++p) {
      int row = p * 32 + srow;
      *(uint4*)&lA[row * 64 + scol] = *(const uint4*)&A[(size_t)(m0 + row) * K + k0 + scol];
      *(uint4*)&lB[row * 64 + scol] = *(const uint4*)&Bt[(size_t)(n0 + row) * K + k0 + scol];
    }
    __syncthreads();
#pragma unroll
    for (int ks = 0; ks < 2; ++ks) {
      bf16x8 af[4], bfr[4];
#pragma unroll
      for (int i = 0; i < 4; ++i)
        af[i] = *(const bf16x8*)&lA[(wm + i * 16 + r16) * 64 + ks * 32 + quad * 8];
#pragma unroll
      for (int j = 0; j < 4; ++j)
        bfr[j] = *(const bf16x8*)&lB[(wn + j * 16 + r16) * 64 + ks * 32 + quad * 8];
#pragma unroll
      for (int i = 0; i < 4; ++i)
#pragma unroll
        for (int j = 0; j < 4; ++j)
          acc[i][j] = __builtin_amdgcn_mfma_f32_16x16x32_bf16(af[i], bfr[j], acc[i][j], 0, 0, 0);
    }
    __syncthreads();
  }

  // epilogue: C/D layout col = lane&15, row = quad*4 + reg
#pragma unroll
  for (int i = 0; i < 4; ++i) {
    int mbase = m0 + wm + i * 16 + quad * 4;
#pragma unroll
    for (int j = 0; j < 4; ++j) {
      int n = n0 + wn + j * 16 + r16;
#pragma unroll
      for (int r = 0; r < 4; ++r) {
        int m = mbase + r;
        float v = acc[i][j][r];
        if (MODE == 0) {
          if (n < DHID) {
            v = (v + bias0[n]) * a_s[DHID + n];
            u_out[(size_t)m * DHID + n] = f2bf(v);
          } else {
            v = v + bias1[n - DHID];
            dx_buf[(size_t)m * DOUT + (n - DHID)] = f2bf(v);
          }
        } else {
          v = (v + bias0[n] + bf2f(dx_buf[(size_t)m * DOUT + n])) * 0.5f;
          out[(size_t)m * DOUT + n] = v;
        }
      }
    }
  }
}

// ---------- scan kernels (chunked linear recurrence h_t = a*h_{t-1} + u_t) ----------
// pass 1: per (b, chunk, d) local scan from zero; store chunk-local final state
__global__ __launch_bounds__(256) void scan1(const unsigned short* __restrict__ u,
                                             const float* __restrict__ a_s,
                                             float* __restrict__ carry) {
  int idx = blockIdx.x * 256 + threadIdx.x;   // 2^18 total
  int d = idx & (DHID - 1);
  int c = (idx >> 10) & (NCH - 1);
  int b = idx >> 15;
  float a = a_s[d];
  float h = 0.f;
  const unsigned short* up = u + ((size_t)(b * S_ + c * CHUNK)) * DHID + d;
#pragma unroll 4
  for (int t = 0; t < CHUNK; ++t)
    h = fmaf(a, h, bf2f(up[(size_t)t * DHID]));
  carry[((size_t)b * NCH + c) * DHID + d] = h;
}

// pass 1.5: sequential prefix over chunks; carry[b][c][d] becomes the exact full
// state at entry of chunk c (seeded with h0)
__global__ __launch_bounds__(256) void scan_mid(const float* __restrict__ a_s,
                                                const float* __restrict__ h0,
                                                float* __restrict__ carry) {
  int idx = blockIdx.x * 256 + threadIdx.x;   // B_*DHID = 8192
  int d = idx & (DHID - 1);
  int b = idx >> 10;
  float a = a_s[d];
  float aL = a;
#pragma unroll
  for (int q = 0; q < 7; ++q) aL *= aL;       // a^128
  float st = h0[(size_t)b * DHID + d];
#pragma unroll
  for (int c = 0; c < NCH; ++c) {
    float* p = &carry[((size_t)b * NCH + c) * DHID + d];
    float loc = *p;
    *p = st;
    st = fmaf(aL, st, loc);
  }
}

// pass 2: recompute full scan from exact chunk-entry state; overwrite u with h (bf16);
// write h_last fp32
__global__ __launch_bounds__(256) void scan2(unsigned short* __restrict__ u,
                                             const float* __restrict__ a_s,
                                             const float* __restrict__ carry,
                                             float* __restrict__ h_last) {
  int idx = blockIdx.x * 256 + threadIdx.x;
  int d = idx & (DHID - 1);
  int c = (idx >> 10) & (NCH - 1);
  int b = idx >> 15;
  float a = a_s[d];
  float h = carry[((size_t)b * NCH + c) * DHID + d];
  unsigned short* up = u + ((size_t)(b * S_ + c * CHUNK)) * DHID + d;
#pragma unroll 4
  for (int t = 0; t < CHUNK; ++t) {
    h = fmaf(a, h, bf2f(up[(size_t)t * DHID]));
    up[(size_t)t * DHID] = f2bf(h);
  }
  if (c == NCH - 1) h_last[(size_t)b * DHID + d] = h;
}

extern "C" void kernel_launch(void* const* d_in, const int* in_sizes, int n_in,
                              void* d_out, int out_size, void* d_ws, size_t ws_size,
                              hipStream_t stream) {
  const float* x    = (const float*)d_in[0];
  const float* h0   = (const float*)d_in[1];
  const float* alog = (const float*)d_in[2];
  const float* Wdx  = (const float*)d_in[3];
  const float* bdx  = (const float*)d_in[4];
  const float* Win  = (const float*)d_in[5];
  const float* bin  = (const float*)d_in[6];
  const float* Wout = (const float*)d_in[7];
  const float* bout = (const float*)d_in[8];

  float* out    = (float*)d_out;
  float* h_last = out + (size_t)M_ * DOUT;

  char* ws = (char*)d_ws;
  // ws layout (bytes):
  unsigned short* xb    = (unsigned short*)(ws);                      // 32 MB  x bf16
  unsigned short* ubuf  = (unsigned short*)(ws + 33554432ull);        // 64 MB  u -> h bf16 (in-place)
  unsigned short* dxb   = (unsigned short*)(ws + 100663296ull);       // 32 MB  dx bf16
  unsigned short* wcat  = (unsigned short*)(ws + 134217728ull);       // 1.5 MB W_in||W_dx transposed bf16
  unsigned short* woutt = (unsigned short*)(ws + 135790592ull);       // 1 MB   W_out transposed bf16
  float*          a_s   = (float*)(ws + 136839168ull);                // 8 KB   [a | sqrt(1-a^2)]
  float*          carry = (float*)(ws + 136847360ull);                // 1 MB   chunk carries

  prep_as  <<<4, 256, 0, stream>>>(alog, a_s);
  prep_x   <<<(M_ * DIN / 8) / 256, 256, 0, stream>>>(x, xb);
  prep_wcat<<<(NCAT * DIN) / 256, 256, 0, stream>>>(Win, Wdx, wcat);
  prep_wout<<<(DOUT * DHID) / 256, 256, 0, stream>>>(Wout, woutt);

  // GEMM1: u = (x@W_in + b_in)*s (bf16), dx = x@W_dx + b_dx (bf16)
  gemm_bt<DIN, 0><<<dim3(M_ / 128, NCAT / 128), 256, 0, stream>>>(
      xb, wcat, a_s, bin, bdx, ubuf, dxb, nullptr);

  // linear scan
  scan1   <<<(B_ * NCH * DHID) / 256, 256, 0, stream>>>(ubuf, a_s, carry);
  scan_mid<<<(B_ * DHID) / 256, 256, 0, stream>>>(a_s, h0, carry);
  scan2   <<<(B_ * NCH * DHID) / 256, 256, 0, stream>>>(ubuf, a_s, carry, h_last);

  // GEMM2: out = (dx + h@W_out + b_out)/2
  gemm_bt<DHID, 1><<<dim3(M_ / 128, DOUT / 128), 256, 0, stream>>>(
      ubuf, woutt, a_s, bout, nullptr, nullptr, dxb, out);
}

// Round 2
// 320.151 us; speedup vs baseline: 1.2129x; 1.2129x over previous
//
#include <hip/hip_runtime.h>

// Problem constants (B,S,D_IN,D_HID,D_OUT) = (8,4096,512,1024,512)
#define B_    8
#define S_    4096
#define DIN   512
#define DHID  1024
#define DOUT  512
#define M_    (B_*S_)          // 32768
#define NCAT  (DHID + DOUT)    // 1536
#define CHUNK 128
#define NCH   (S_/CHUNK)       // 32

typedef __bf16 bf16x8 __attribute__((ext_vector_type(8)));
typedef float  floatx4 __attribute__((ext_vector_type(4)));

__device__ __forceinline__ unsigned short f2bf(float f) {
  unsigned u = __builtin_bit_cast(unsigned, f);
  u = (u + 0x7FFFu + ((u >> 16) & 1u)) >> 16;   // RNE
  return (unsigned short)u;
}
__device__ __forceinline__ float bf2f(unsigned short h) {
  unsigned u = ((unsigned)h) << 16;
  return __builtin_bit_cast(float, u);
}

// async global->LDS, 16 B per lane; LDS dest = wave-uniform base + lane*16
__device__ __forceinline__ void gl_lds16(const unsigned short* g, unsigned short* l) {
  __builtin_amdgcn_global_load_lds((const __attribute__((address_space(1))) void*)g,
                                   (__attribute__((address_space(3))) void*)l, 16, 0, 0);
}

// ---------- prep kernels ----------
__global__ void prep_as(const float* __restrict__ logit, float* __restrict__ a_s) {
  int d = blockIdx.x * 256 + threadIdx.x;
  if (d < DHID) {
    float a = 1.f / (1.f + expf(-logit[d]));
    a_s[d] = a;
    a_s[DHID + d] = sqrtf(fmaxf(1.f - a * a, 0.f));
  }
}

// x fp32 -> bf16, 8 elems/thread
__global__ void prep_x(const float* __restrict__ x, unsigned short* __restrict__ xb) {
  size_t i = (size_t)blockIdx.x * 256 + threadIdx.x;
  const float4* p = (const float4*)x;
  float4 v0 = p[i * 2];
  float4 v1 = p[i * 2 + 1];
  uint4 o;
  o.x = (unsigned)f2bf(v0.x) | ((unsigned)f2bf(v0.y) << 16);
  o.y = (unsigned)f2bf(v0.z) | ((unsigned)f2bf(v0.w) << 16);
  o.z = (unsigned)f2bf(v1.x) | ((unsigned)f2bf(v1.y) << 16);
  o.w = (unsigned)f2bf(v1.z) | ((unsigned)f2bf(v1.w) << 16);
  *(uint4*)&xb[i * 8] = o;
}

// Wcat^T bf16: rows n in [0,1536), cols k in [0,512). n<1024 -> W_in[:,n], else W_dx[:,n-1024]
__global__ void prep_wcat(const float* __restrict__ Win, const float* __restrict__ Wdx,
                          unsigned short* __restrict__ wcat) {
  int idx = blockIdx.x * 256 + threadIdx.x;   // n*512 + k
  int n = idx >> 9, k = idx & 511;
  float v = (n < DHID) ? Win[(size_t)k * DHID + n] : Wdx[(size_t)k * DOUT + (n - DHID)];
  wcat[idx] = f2bf(v);
}

// Wout^T bf16: rows n in [0,512), cols k in [0,1024)
__global__ void prep_wout(const float* __restrict__ Wout, unsigned short* __restrict__ wt) {
  int idx = blockIdx.x * 256 + threadIdx.x;   // n*1024 + k
  int n = idx >> 10, k = idx & 1023;
  wt[idx] = f2bf(Wout[(size_t)k * DOUT + n]);
}

// ---------- GEMM (128x128 tile, 4 waves of 64x64, mfma 16x16x32 bf16) ----------
// global_load_lds staging with XOR-8 swizzle on colblocks; grid = (N/128, M/128)
// MODE 0: C = A(MxK) * Wcat^T; n<1024: u=(c+b_in)*s bf16 ; n>=1024: dx=c+b_dx bf16
// MODE 1: C = H(MxK) * Wout^T; out = (c + b_out + dx)*0.5 fp32
template <int K, int MODE>
__global__ __launch_bounds__(256) void gemm_bt(
    const unsigned short* __restrict__ A,    // M x K bf16 row-major
    const unsigned short* __restrict__ Bt,   // N x K bf16 row-major
    const float* __restrict__ a_s,           // [a | s]
    const float* __restrict__ bias0,         // b_in (MODE0) / b_out (MODE1)
    const float* __restrict__ bias1,         // b_dx (MODE0)
    unsigned short* __restrict__ u_out,      // MODE0
    unsigned short* __restrict__ dx_buf,     // MODE0 out / MODE1 in
    float* __restrict__ out)                 // MODE1
{
  __shared__ __align__(16) unsigned char smem[32768];
  unsigned short* lA = (unsigned short*)smem;            // 128 x 64 bf16
  unsigned short* lB = (unsigned short*)(smem + 16384);  // 128 x 64 bf16
  float* stg = (float*)smem;                             // epilogue stage, 32 x 132 fp32

  const int tid = threadIdx.x;
  const int n0 = blockIdx.x * 128, m0 = blockIdx.y * 128;
  const int wid = tid >> 6, lane = tid & 63;
  const int wm = (wid >> 1) * 64, wn = (wid & 1) * 64;
  const int r16 = lane & 15, quad = lane >> 4;
  const int sw = r16 & 7;

  // staging geometry: per instr, 8 rows x 64 cols; lane l -> row +(l>>3), colblk (l&7)^(l>>3)
  const int rsub = lane >> 3;
  const int gcol = ((lane & 7) ^ rsub) << 3;

  const unsigned short* Abase = A + (size_t)(m0 + (wid << 5) + rsub) * K + gcol;
  const unsigned short* Bbase = Bt + (size_t)(n0 + (wid << 5) + rsub) * K + gcol;
  unsigned short* lAw = lA + (wid << 5) * 64;
  unsigned short* lBw = lB + (wid << 5) * 64;

  floatx4 acc[4][4] = {};

  for (int k0 = 0; k0 < K; k0 += 64) {
#pragma unroll
    for (int i = 0; i < 4; ++i) {
      gl_lds16(Abase + (size_t)(i * 8) * K + k0, lAw + i * 8 * 64);
      gl_lds16(Bbase + (size_t)(i * 8) * K + k0, lBw + i * 8 * 64);
    }
    __syncthreads();
#pragma unroll
    for (int ks = 0; ks < 2; ++ks) {
      bf16x8 af[4], bfr[4];
#pragma unroll
      for (int i = 0; i < 4; ++i)
        af[i] = *(const bf16x8*)&lA[(wm + i * 16 + r16) * 64 + ((((ks << 2) | quad) ^ sw) << 3)];
#pragma unroll
      for (int j = 0; j < 4; ++j)
        bfr[j] = *(const bf16x8*)&lB[(wn + j * 16 + r16) * 64 + ((((ks << 2) | quad) ^ sw) << 3)];
#pragma unroll
      for (int i = 0; i < 4; ++i)
#pragma unroll
        for (int j = 0; j < 4; ++j)
          acc[i][j] = __builtin_amdgcn_mfma_f32_16x16x32_bf16(af[i], bfr[j], acc[i][j], 0, 0, 0);
    }
    __syncthreads();
  }

  // ---- epilogue: 4 passes of 32 rows through LDS (fp32, stride 132), coalesced stores ----
  const int row = tid >> 3;   // 0..31
  const int seg = tid & 7;    // 0..7
#pragma unroll
  for (int p = 0; p < 4; ++p) {
    __syncthreads();
    if ((wid >> 1) == (p >> 1)) {
      const int i0 = (p & 1) * 2;
#pragma unroll
      for (int ii = 0; ii < 2; ++ii) {
        const int i = i0 + ii;
        const int srow = i * 16 + quad * 4 - (p & 1) * 32;
#pragma unroll
        for (int j = 0; j < 4; ++j) {
          const int scol = wn + j * 16 + r16;
#pragma unroll
          for (int r = 0; r < 4; ++r)
            stg[(srow + r) * 132 + scol] = acc[i][j][r];
        }
      }
    }
    __syncthreads();
    const int gm = m0 + p * 32 + row;
    const int col0 = n0 + seg * 16;
    if (MODE == 0) {
      union { unsigned short s[16]; uint4 q[2]; } ub;
      if (n0 < DHID) {
#pragma unroll
        for (int u = 0; u < 4; ++u) {
          float4 v  = *(const float4*)&stg[row * 132 + seg * 16 + u * 4];
          float4 bi = *(const float4*)&bias0[col0 + u * 4];
          float4 sc = *(const float4*)&a_s[DHID + col0 + u * 4];
          ub.s[u * 4 + 0] = f2bf((v.x + bi.x) * sc.x);
          ub.s[u * 4 + 1] = f2bf((v.y + bi.y) * sc.y);
          ub.s[u * 4 + 2] = f2bf((v.z + bi.z) * sc.z);
          ub.s[u * 4 + 3] = f2bf((v.w + bi.w) * sc.w);
        }
        *(uint4*)&u_out[(size_t)gm * DHID + col0]     = ub.q[0];
        *(uint4*)&u_out[(size_t)gm * DHID + col0 + 8] = ub.q[1];
      } else {
        const int c2 = col0 - DHID;
#pragma unroll
        for (int u = 0; u < 4; ++u) {
          float4 v  = *(const float4*)&stg[row * 132 + seg * 16 + u * 4];
          float4 bd = *(const float4*)&bias1[c2 + u * 4];
          ub.s[u * 4 + 0] = f2bf(v.x + bd.x);
          ub.s[u * 4 + 1] = f2bf(v.y + bd.y);
          ub.s[u * 4 + 2] = f2bf(v.z + bd.z);
          ub.s[u * 4 + 3] = f2bf(v.w + bd.w);
        }
        *(uint4*)&dx_buf[(size_t)gm * DOUT + c2]     = ub.q[0];
        *(uint4*)&dx_buf[(size_t)gm * DOUT + c2 + 8] = ub.q[1];
      }
    } else {
#pragma unroll
      for (int u = 0; u < 4; ++u) {
        float4 v  = *(const float4*)&stg[row * 132 + seg * 16 + u * 4];
        float4 bo = *(const float4*)&bias0[col0 + u * 4];
        ushort4 dv = *(const ushort4*)&dx_buf[(size_t)gm * DOUT + col0 + u * 4];
        float4 o;
        o.x = (v.x + bo.x + bf2f(dv.x)) * 0.5f;
        o.y = (v.y + bo.y + bf2f(dv.y)) * 0.5f;
        o.z = (v.z + bo.z + bf2f(dv.z)) * 0.5f;
        o.w = (v.w + bo.w + bf2f(dv.w)) * 0.5f;
        *(float4*)&out[(size_t)gm * DOUT + col0 + u * 4] = o;
      }
    }
  }
}

// ---------- scan kernels (chunked linear recurrence h_t = a*h_{t-1} + u_t) ----------
__global__ __launch_bounds__(256) void scan1(const unsigned short* __restrict__ u,
                                             const float* __restrict__ a_s,
                                             float* __restrict__ carry) {
  int idx = blockIdx.x * 256 + threadIdx.x;
  int d = idx & (DHID - 1);
  int c = (idx >> 10) & (NCH - 1);
  int b = idx >> 15;
  float a = a_s[d];
  float h = 0.f;
  const unsigned short* up = u + ((size_t)(b * S_ + c * CHUNK)) * DHID + d;
#pragma unroll 4
  for (int t = 0; t < CHUNK; ++t)
    h = fmaf(a, h, bf2f(up[(size_t)t * DHID]));
  carry[((size_t)b * NCH + c) * DHID + d] = h;
}

__global__ __launch_bounds__(256) void scan_mid(const float* __restrict__ a_s,
                                                const float* __restrict__ h0,
                                                float* __restrict__ carry) {
  int idx = blockIdx.x * 256 + threadIdx.x;   // B_*DHID = 8192
  int d = idx & (DHID - 1);
  int b = idx >> 10;
  float a = a_s[d];
  float aL = a;
#pragma unroll
  for (int q = 0; q < 7; ++q) aL *= aL;       // a^128
  float st = h0[(size_t)b * DHID + d];
#pragma unroll
  for (int c = 0; c < NCH; ++c) {
    float* p = &carry[((size_t)b * NCH + c) * DHID + d];
    float loc = *p;
    *p = st;
    st = fmaf(aL, st, loc);
  }
}

__global__ __launch_bounds__(256) void scan2(unsigned short* __restrict__ u,
                                             const float* __restrict__ a_s,
                                             const float* __restrict__ carry,
                                             float* __restrict__ h_last) {
  int idx = blockIdx.x * 256 + threadIdx.x;
  int d = idx & (DHID - 1);
  int c = (idx >> 10) & (NCH - 1);
  int b = idx >> 15;
  float a = a_s[d];
  float h = carry[((size_t)b * NCH + c) * DHID + d];
  unsigned short* up = u + ((size_t)(b * S_ + c * CHUNK)) * DHID + d;
#pragma unroll 4
  for (int t = 0; t < CHUNK; ++t) {
    h = fmaf(a, h, bf2f(up[(size_t)t * DHID]));
    up[(size_t)t * DHID] = f2bf(h);
  }
  if (c == NCH - 1) h_last[(size_t)b * DHID + d] = h;
}

extern "C" void kernel_launch(void* const* d_in, const int* in_sizes, int n_in,
                              void* d_out, int out_size, void* d_ws, size_t ws_size,
                              hipStream_t stream) {
  const float* x    = (const float*)d_in[0];
  const float* h0   = (const float*)d_in[1];
  const float* alog = (const float*)d_in[2];
  const float* Wdx  = (const float*)d_in[3];
  const float* bdx  = (const float*)d_in[4];
  const float* Win  = (const float*)d_in[5];
  const float* bin  = (const float*)d_in[6];
  const float* Wout = (const float*)d_in[7];
  const float* bout = (const float*)d_in[8];

  float* out    = (float*)d_out;
  float* h_last = out + (size_t)M_ * DOUT;

  char* ws = (char*)d_ws;
  unsigned short* xb    = (unsigned short*)(ws);                      // 32 MB
  unsigned short* ubuf  = (unsigned short*)(ws + 33554432ull);        // 64 MB (u -> h in-place)
  unsigned short* dxb   = (unsigned short*)(ws + 100663296ull);       // 32 MB
  unsigned short* wcat  = (unsigned short*)(ws + 134217728ull);       // 1.5 MB
  unsigned short* woutt = (unsigned short*)(ws + 135790592ull);       // 1 MB
  float*          a_s   = (float*)(ws + 136839168ull);                // 8 KB
  float*          carry = (float*)(ws + 136847360ull);                // 1 MB

  prep_as  <<<4, 256, 0, stream>>>(alog, a_s);
  prep_x   <<<(M_ * DIN / 8) / 256, 256, 0, stream>>>(x, xb);
  prep_wcat<<<(NCAT * DIN) / 256, 256, 0, stream>>>(Win, Wdx, wcat);
  prep_wout<<<(DOUT * DHID) / 256, 256, 0, stream>>>(Wout, woutt);

  // GEMM1: u = (x@W_in + b_in)*s (bf16), dx = x@W_dx + b_dx (bf16)
  gemm_bt<DIN, 0><<<dim3(NCAT / 128, M_ / 128), 256, 0, stream>>>(
      xb, wcat, a_s, bin, bdx, ubuf, dxb, nullptr);

  // linear scan
  scan1   <<<(B_ * NCH * DHID) / 256, 256, 0, stream>>>(ubuf, a_s, carry);
  scan_mid<<<(B_ * DHID) / 256, 256, 0, stream>>>(a_s, h0, carry);
  scan2   <<<(B_ * NCH * DHID) / 256, 256, 0, stream>>>(ubuf, a_s, carry, h_last);

  // GEMM2: out = (dx + h@W_out + b_out)/2
  gemm_bt<DHID, 1><<<dim3(DOUT / 128, M_ / 128), 256, 0, stream>>>(
      ubuf, woutt, a_s, bout, nullptr, nullptr, dxb, out);
}

// Round 3
// 303.396 us; speedup vs baseline: 1.2799x; 1.0552x over previous
//
#include <hip/hip_runtime.h>

// Problem constants (B,S,D_IN,D_HID,D_OUT) = (8,4096,512,1024,512)
#define B_    8
#define S_    4096
#define DIN   512
#define DHID  1024
#define DOUT  512
#define M_    (B_*S_)          // 32768
#define NCAT  (DHID + DOUT)    // 1536
#define CH2   32
#define NCH2  (S_/CH2)         // 128

typedef __bf16 bf16x8 __attribute__((ext_vector_type(8)));
typedef float  floatx4 __attribute__((ext_vector_type(4)));

__device__ __forceinline__ unsigned short f2bf(float f) {
  unsigned u = __builtin_bit_cast(unsigned, f);
  u = (u + 0x7FFFu + ((u >> 16) & 1u)) >> 16;   // RNE
  return (unsigned short)u;
}
__device__ __forceinline__ float bf2f(unsigned short h) {
  unsigned u = ((unsigned)h) << 16;
  return __builtin_bit_cast(float, u);
}

__device__ __forceinline__ void gl_lds16(const unsigned short* g, unsigned short* l) {
  __builtin_amdgcn_global_load_lds((const __attribute__((address_space(1))) void*)g,
                                   (__attribute__((address_space(3))) void*)l, 16, 0, 0);
}

// ---------- prep kernels ----------
__global__ void prep_as(const float* __restrict__ logit, float* __restrict__ a_s) {
  int d = blockIdx.x * 256 + threadIdx.x;
  if (d < DHID) {
    float a = 1.f / (1.f + expf(-logit[d]));
    a_s[d] = a;
    a_s[DHID + d] = sqrtf(fmaxf(1.f - a * a, 0.f));
  }
}

__global__ void prep_x(const float* __restrict__ x, unsigned short* __restrict__ xb) {
  size_t i = (size_t)blockIdx.x * 256 + threadIdx.x;
  const float4* p = (const float4*)x;
  float4 v0 = p[i * 2];
  float4 v1 = p[i * 2 + 1];
  uint4 o;
  o.x = (unsigned)f2bf(v0.x) | ((unsigned)f2bf(v0.y) << 16);
  o.y = (unsigned)f2bf(v0.z) | ((unsigned)f2bf(v0.w) << 16);
  o.z = (unsigned)f2bf(v1.x) | ((unsigned)f2bf(v1.y) << 16);
  o.w = (unsigned)f2bf(v1.z) | ((unsigned)f2bf(v1.w) << 16);
  *(uint4*)&xb[i * 8] = o;
}

__global__ void prep_wcat(const float* __restrict__ Win, const float* __restrict__ Wdx,
                          unsigned short* __restrict__ wcat) {
  int idx = blockIdx.x * 256 + threadIdx.x;   // n*512 + k
  int n = idx >> 9, k = idx & 511;
  float v = (n < DHID) ? Win[(size_t)k * DHID + n] : Wdx[(size_t)k * DOUT + (n - DHID)];
  wcat[idx] = f2bf(v);
}

__global__ void prep_wout(const float* __restrict__ Wout, unsigned short* __restrict__ wt) {
  int idx = blockIdx.x * 256 + threadIdx.x;   // n*1024 + k
  int n = idx >> 10, k = idx & 1023;
  wt[idx] = f2bf(Wout[(size_t)k * DOUT + n]);
}

// ---------- GEMM (128x128 tile, 4 waves of 64x64, mfma 16x16x32 bf16) ----------
// XCD-aware swizzle: flat%8 = xcd; within an XCD, all NB n-blocks of one m-tile are
// consecutive (A-tile fetched by exactly one XCD; B L2-resident per XCD).
// MODE 0: C = A(MxK) * Wcat^T; n<1024: u=(c+b_in)*s bf16 ; n>=1024: dx=c+b_dx bf16
// MODE 1: C = H(MxK) * Wout^T; out = (c + b_out + dx)*0.5 fp32
template <int K, int MODE, int NB>
__global__ __launch_bounds__(256) void gemm_bt(
    const unsigned short* __restrict__ A,
    const unsigned short* __restrict__ Bt,
    const float* __restrict__ a_s,
    const float* __restrict__ bias0,
    const float* __restrict__ bias1,
    unsigned short* __restrict__ u_out,
    unsigned short* __restrict__ dx_buf,
    float* __restrict__ out)
{
  __shared__ __align__(16) unsigned char smem[32768];
  unsigned short* lA = (unsigned short*)smem;            // 128 x 64 bf16
  unsigned short* lB = (unsigned short*)(smem + 16384);  // 128 x 64 bf16
  float* stg = (float*)smem;                             // epilogue stage, 32 x 132 fp32

  const int tid = threadIdx.x;
  const int flat = blockIdx.y * gridDim.x + blockIdx.x;
  const int xcd = flat & 7;
  const int j = flat >> 3;
  const int n0 = (j % NB) * 128;
  const int m0 = ((j / NB) * 8 + xcd) * 128;

  const int wid = tid >> 6, lane = tid & 63;
  const int wm = (wid >> 1) * 64, wn = (wid & 1) * 64;
  const int r16 = lane & 15, quad = lane >> 4;
  const int sw = r16 & 7;

  // staging geometry: per instr, 8 rows x 64 cols; lane l -> row +(l>>3), colblk (l&7)^(l>>3)
  const int rsub = lane >> 3;
  const int gcol = ((lane & 7) ^ rsub) << 3;

  const unsigned short* Abase = A + (size_t)(m0 + (wid << 5) + rsub) * K + gcol;
  const unsigned short* Bbase = Bt + (size_t)(n0 + (wid << 5) + rsub) * K + gcol;
  unsigned short* lAw = lA + (wid << 5) * 64;
  unsigned short* lBw = lB + (wid << 5) * 64;

  floatx4 acc[4][4] = {};

  for (int k0 = 0; k0 < K; k0 += 64) {
#pragma unroll
    for (int i = 0; i < 4; ++i) {
      gl_lds16(Abase + (size_t)(i * 8) * K + k0, lAw + i * 8 * 64);
      gl_lds16(Bbase + (size_t)(i * 8) * K + k0, lBw + i * 8 * 64);
    }
    __syncthreads();
#pragma unroll
    for (int ks = 0; ks < 2; ++ks) {
      bf16x8 af[4], bfr[4];
#pragma unroll
      for (int i = 0; i < 4; ++i)
        af[i] = *(const bf16x8*)&lA[(wm + i * 16 + r16) * 64 + ((((ks << 2) | quad) ^ sw) << 3)];
#pragma unroll
      for (int j2 = 0; j2 < 4; ++j2)
        bfr[j2] = *(const bf16x8*)&lB[(wn + j2 * 16 + r16) * 64 + ((((ks << 2) | quad) ^ sw) << 3)];
#pragma unroll
      for (int i = 0; i < 4; ++i)
#pragma unroll
        for (int j2 = 0; j2 < 4; ++j2)
          acc[i][j2] = __builtin_amdgcn_mfma_f32_16x16x32_bf16(af[i], bfr[j2], acc[i][j2], 0, 0, 0);
    }
    __syncthreads();
  }

  // ---- epilogue: 4 passes of 32 rows through LDS (fp32, stride 132), coalesced stores ----
  const int row = tid >> 3;   // 0..31
  const int seg = tid & 7;    // 0..7
#pragma unroll
  for (int p = 0; p < 4; ++p) {
    __syncthreads();
    if ((wid >> 1) == (p >> 1)) {
      const int i0 = (p & 1) * 2;
#pragma unroll
      for (int ii = 0; ii < 2; ++ii) {
        const int i = i0 + ii;
        const int srow = i * 16 + quad * 4 - (p & 1) * 32;
#pragma unroll
        for (int j2 = 0; j2 < 4; ++j2) {
          const int scol = wn + j2 * 16 + r16;
#pragma unroll
          for (int r = 0; r < 4; ++r)
            stg[(srow + r) * 132 + scol] = acc[i][j2][r];
        }
      }
    }
    __syncthreads();
    const int gm = m0 + p * 32 + row;
    const int col0 = n0 + seg * 16;
    if (MODE == 0) {
      union { unsigned short s[16]; uint4 q[2]; } ub;
      if (n0 < DHID) {
#pragma unroll
        for (int u = 0; u < 4; ++u) {
          float4 v  = *(const float4*)&stg[row * 132 + seg * 16 + u * 4];
          float4 bi = *(const float4*)&bias0[col0 + u * 4];
          float4 sc = *(const float4*)&a_s[DHID + col0 + u * 4];
          ub.s[u * 4 + 0] = f2bf((v.x + bi.x) * sc.x);
          ub.s[u * 4 + 1] = f2bf((v.y + bi.y) * sc.y);
          ub.s[u * 4 + 2] = f2bf((v.z + bi.z) * sc.z);
          ub.s[u * 4 + 3] = f2bf((v.w + bi.w) * sc.w);
        }
        *(uint4*)&u_out[(size_t)gm * DHID + col0]     = ub.q[0];
        *(uint4*)&u_out[(size_t)gm * DHID + col0 + 8] = ub.q[1];
      } else {
        const int c2 = col0 - DHID;
#pragma unroll
        for (int u = 0; u < 4; ++u) {
          float4 v  = *(const float4*)&stg[row * 132 + seg * 16 + u * 4];
          float4 bd = *(const float4*)&bias1[c2 + u * 4];
          ub.s[u * 4 + 0] = f2bf(v.x + bd.x);
          ub.s[u * 4 + 1] = f2bf(v.y + bd.y);
          ub.s[u * 4 + 2] = f2bf(v.z + bd.z);
          ub.s[u * 4 + 3] = f2bf(v.w + bd.w);
        }
        *(uint4*)&dx_buf[(size_t)gm * DOUT + c2]     = ub.q[0];
        *(uint4*)&dx_buf[(size_t)gm * DOUT + c2 + 8] = ub.q[1];
      }
    } else {
#pragma unroll
      for (int u = 0; u < 4; ++u) {
        float4 v  = *(const float4*)&stg[row * 132 + seg * 16 + u * 4];
        float4 bo = *(const float4*)&bias0[col0 + u * 4];
        ushort4 dv = *(const ushort4*)&dx_buf[(size_t)gm * DOUT + col0 + u * 4];
        float4 o;
        o.x = (v.x + bo.x + bf2f(dv.x)) * 0.5f;
        o.y = (v.y + bo.y + bf2f(dv.y)) * 0.5f;
        o.z = (v.z + bo.z + bf2f(dv.z)) * 0.5f;
        o.w = (v.w + bo.w + bf2f(dv.w)) * 0.5f;
        *(float4*)&out[(size_t)gm * DOUT + col0 + u * 4] = o;
      }
    }
  }
}

// ---------- scan kernels: 8 d's per thread, 16 B/lane fully-coalesced ----------
// pass 1: per (b, chunk, d8) local scan from zero; store chunk-local final state (fp32)
__global__ __launch_bounds__(256) void scan1(const unsigned short* __restrict__ u,
                                             const float* __restrict__ a_s,
                                             float* __restrict__ carry) {
  int idx = blockIdx.x * 256 + threadIdx.x;       // B*NCH2*(DHID/8) = 131072
  int d8 = (idx & 127) * 8;
  int c  = (idx >> 7) & (NCH2 - 1);
  int b  = idx >> 14;
  float4 a0 = *(const float4*)&a_s[d8];
  float4 a1 = *(const float4*)&a_s[d8 + 4];
  float h0_ = 0.f, h1 = 0.f, h2 = 0.f, h3 = 0.f, h4 = 0.f, h5 = 0.f, h6 = 0.f, h7 = 0.f;
  const unsigned short* up = u + ((size_t)(b * S_ + c * CH2)) * DHID + d8;
#pragma unroll 4
  for (int t = 0; t < CH2; ++t) {
    ushort4 q0 = *(const ushort4*)up;
    ushort4 q1 = *(const ushort4*)(up + 4);
    h0_ = fmaf(a0.x, h0_, bf2f(q0.x)); h1 = fmaf(a0.y, h1, bf2f(q0.y));
    h2  = fmaf(a0.z, h2,  bf2f(q0.z)); h3 = fmaf(a0.w, h3, bf2f(q0.w));
    h4  = fmaf(a1.x, h4,  bf2f(q1.x)); h5 = fmaf(a1.y, h5, bf2f(q1.y));
    h6  = fmaf(a1.z, h6,  bf2f(q1.z)); h7 = fmaf(a1.w, h7, bf2f(q1.w));
    up += DHID;
  }
  float* cp = &carry[((size_t)(b * NCH2 + c)) * DHID + d8];
  float4 o0 = {h0_, h1, h2, h3}, o1 = {h4, h5, h6, h7};
  *(float4*)cp = o0;
  *(float4*)(cp + 4) = o1;
}

// pass 1.5: sequential prefix over chunks; carry becomes exact chunk-entry state.
// Also writes h_last (final state).
__global__ __launch_bounds__(256) void scan_mid(const float* __restrict__ a_s,
                                                const float* __restrict__ h0,
                                                float* __restrict__ carry,
                                                float* __restrict__ h_last) {
  int idx = blockIdx.x * 256 + threadIdx.x;   // B_*DHID = 8192
  int d = idx & (DHID - 1);
  int b = idx >> 10;
  float a = a_s[d];
  float aL = a;
#pragma unroll
  for (int q = 0; q < 5; ++q) aL *= aL;       // a^32
  float st = h0[(size_t)b * DHID + d];
  for (int c = 0; c < NCH2; ++c) {
    float* p = &carry[((size_t)b * NCH2 + c) * DHID + d];
    float loc = *p;
    *p = st;
    st = fmaf(aL, st, loc);
  }
  h_last[(size_t)b * DHID + d] = st;
}

// pass 2: recompute scan from exact entry state; overwrite u with h (bf16)
__global__ __launch_bounds__(256) void scan2(unsigned short* __restrict__ u,
                                             const float* __restrict__ a_s,
                                             const float* __restrict__ carry) {
  int idx = blockIdx.x * 256 + threadIdx.x;
  int d8 = (idx & 127) * 8;
  int c  = (idx >> 7) & (NCH2 - 1);
  int b  = idx >> 14;
  float4 a0 = *(const float4*)&a_s[d8];
  float4 a1 = *(const float4*)&a_s[d8 + 4];
  const float* cp = &carry[((size_t)(b * NCH2 + c)) * DHID + d8];
  float4 e0 = *(const float4*)cp;
  float4 e1 = *(const float4*)(cp + 4);
  float h0_ = e0.x, h1 = e0.y, h2 = e0.z, h3 = e0.w;
  float h4 = e1.x, h5 = e1.y, h6 = e1.z, h7 = e1.w;
  unsigned short* up = u + ((size_t)(b * S_ + c * CH2)) * DHID + d8;
#pragma unroll 4
  for (int t = 0; t < CH2; ++t) {
    ushort4 q0 = *(const ushort4*)up;
    ushort4 q1 = *(const ushort4*)(up + 4);
    h0_ = fmaf(a0.x, h0_, bf2f(q0.x)); h1 = fmaf(a0.y, h1, bf2f(q0.y));
    h2  = fmaf(a0.z, h2,  bf2f(q0.z)); h3 = fmaf(a0.w, h3, bf2f(q0.w));
    h4  = fmaf(a1.x, h4,  bf2f(q1.x)); h5 = fmaf(a1.y, h5, bf2f(q1.y));
    h6  = fmaf(a1.z, h6,  bf2f(q1.z)); h7 = fmaf(a1.w, h7, bf2f(q1.w));
    ushort4 w0, w1;
    w0.x = f2bf(h0_); w0.y = f2bf(h1); w0.z = f2bf(h2); w0.w = f2bf(h3);
    w1.x = f2bf(h4);  w1.y = f2bf(h5); w1.z = f2bf(h6); w1.w = f2bf(h7);
    *(ushort4*)up = w0;
    *(ushort4*)(up + 4) = w1;
    up += DHID;
  }
}

extern "C" void kernel_launch(void* const* d_in, const int* in_sizes, int n_in,
                              void* d_out, int out_size, void* d_ws, size_t ws_size,
                              hipStream_t stream) {
  const float* x    = (const float*)d_in[0];
  const float* h0   = (const float*)d_in[1];
  const float* alog = (const float*)d_in[2];
  const float* Wdx  = (const float*)d_in[3];
  const float* bdx  = (const float*)d_in[4];
  const float* Win  = (const float*)d_in[5];
  const float* bin  = (const float*)d_in[6];
  const float* Wout = (const float*)d_in[7];
  const float* bout = (const float*)d_in[8];

  float* out    = (float*)d_out;
  float* h_last = out + (size_t)M_ * DOUT;

  char* ws = (char*)d_ws;
  unsigned short* xb    = (unsigned short*)(ws);                      // 32 MB (dead after GEMM1)
  unsigned short* ubuf  = (unsigned short*)(ws + 33554432ull);        // 64 MB (u -> h in-place)
  unsigned short* dxb   = (unsigned short*)(ws + 100663296ull);       // 32 MB
  unsigned short* wcat  = (unsigned short*)(ws + 134217728ull);       // 1.5 MB
  unsigned short* woutt = (unsigned short*)(ws + 135790592ull);       // 1 MB
  float*          a_s   = (float*)(ws + 136839168ull);                // 8 KB
  float*          carry = (float*)(ws);                               // 4 MB, aliases dead xb

  prep_as  <<<4, 256, 0, stream>>>(alog, a_s);
  prep_x   <<<(M_ * DIN / 8) / 256, 256, 0, stream>>>(x, xb);
  prep_wcat<<<(NCAT * DIN) / 256, 256, 0, stream>>>(Win, Wdx, wcat);
  prep_wout<<<(DOUT * DHID) / 256, 256, 0, stream>>>(Wout, woutt);

  // GEMM1: u = (x@W_in + b_in)*s (bf16), dx = x@W_dx + b_dx (bf16)
  gemm_bt<DIN, 0, 12><<<dim3(NCAT / 128, M_ / 128), 256, 0, stream>>>(
      xb, wcat, a_s, bin, bdx, ubuf, dxb, nullptr);

  // linear scan (chunked, CH2=32)
  scan1   <<<(B_ * NCH2 * (DHID / 8)) / 256, 256, 0, stream>>>(ubuf, a_s, carry);
  scan_mid<<<(B_ * DHID) / 256, 256, 0, stream>>>(a_s, h0, carry, h_last);
  scan2   <<<(B_ * NCH2 * (DHID / 8)) / 256, 256, 0, stream>>>(ubuf, a_s, carry);

  // GEMM2: out = (dx + h@W_out + b_out)/2
  gemm_bt<DHID, 1, 4><<<dim3(DOUT / 128, M_ / 128), 256, 0, stream>>>(
      ubuf, woutt, a_s, bout, nullptr, nullptr, dxb, out);
}

// Round 4
// 296.297 us; speedup vs baseline: 1.3106x; 1.0240x over previous
//
#include <hip/hip_runtime.h>

// Problem constants (B,S,D_IN,D_HID,D_OUT) = (8,4096,512,1024,512)
#define B_    8
#define S_    4096
#define DIN   512
#define DHID  1024
#define DOUT  512
#define M_    (B_*S_)          // 32768
#define NCAT  (DHID + DOUT)    // 1536
#define CH2   32
#define NCH2  (S_/CH2)         // 128

typedef __bf16 bf16x8 __attribute__((ext_vector_type(8)));
typedef float  floatx4 __attribute__((ext_vector_type(4)));

__device__ __forceinline__ unsigned short f2bf(float f) {
  unsigned u = __builtin_bit_cast(unsigned, f);
  u = (u + 0x7FFFu + ((u >> 16) & 1u)) >> 16;   // RNE
  return (unsigned short)u;
}
__device__ __forceinline__ float bf2f(unsigned short h) {
  unsigned u = ((unsigned)h) << 16;
  return __builtin_bit_cast(float, u);
}

__device__ __forceinline__ void gl_lds16(const unsigned short* g, unsigned short* l) {
  __builtin_amdgcn_global_load_lds((const __attribute__((address_space(1))) void*)g,
                                   (__attribute__((address_space(3))) void*)l, 16, 0, 0);
}

// ---------- prep kernels ----------
__global__ void prep_as(const float* __restrict__ logit, float* __restrict__ a_s) {
  int d = blockIdx.x * 256 + threadIdx.x;
  if (d < DHID) {
    float a = 1.f / (1.f + expf(-logit[d]));
    a_s[d] = a;
    a_s[DHID + d] = sqrtf(fmaxf(1.f - a * a, 0.f));
  }
}

__global__ void prep_x(const float* __restrict__ x, unsigned short* __restrict__ xb) {
  size_t i = (size_t)blockIdx.x * 256 + threadIdx.x;
  const float4* p = (const float4*)x;
  float4 v0 = p[i * 2];
  float4 v1 = p[i * 2 + 1];
  uint4 o;
  o.x = (unsigned)f2bf(v0.x) | ((unsigned)f2bf(v0.y) << 16);
  o.y = (unsigned)f2bf(v0.z) | ((unsigned)f2bf(v0.w) << 16);
  o.z = (unsigned)f2bf(v1.x) | ((unsigned)f2bf(v1.y) << 16);
  o.w = (unsigned)f2bf(v1.z) | ((unsigned)f2bf(v1.w) << 16);
  *(uint4*)&xb[i * 8] = o;
}

__global__ void prep_wcat(const float* __restrict__ Win, const float* __restrict__ Wdx,
                          unsigned short* __restrict__ wcat) {
  int idx = blockIdx.x * 256 + threadIdx.x;   // n*512 + k
  int n = idx >> 9, k = idx & 511;
  float v = (n < DHID) ? Win[(size_t)k * DHID + n] : Wdx[(size_t)k * DOUT + (n - DHID)];
  wcat[idx] = f2bf(v);
}

__global__ void prep_wout(const float* __restrict__ Wout, unsigned short* __restrict__ wt) {
  int idx = blockIdx.x * 256 + threadIdx.x;   // n*1024 + k
  int n = idx >> 10, k = idx & 1023;
  wt[idx] = f2bf(Wout[(size_t)k * DOUT + n]);
}

// ---------- GEMM (128x128 tile, 4 waves of 64x64, mfma 16x16x32 bf16) ----------
// XCD-aware swizzle; global_load_lds staging with XOR-8 colblock swizzle.
// __launch_bounds__(256,4): cap unified VGPR+AGPR at 128 -> 4 blocks/CU.
// MODE 0: C = A(MxK) * Wcat^T; n<1024: u=(c+b_in)*s bf16 ; n>=1024: dx=c+b_dx bf16
// MODE 1: C = H(MxK) * Wout^T; out = (c + b_out + dx)*0.5 fp32
template <int K, int MODE, int NB>
__global__ __launch_bounds__(256, 4) void gemm_bt(
    const unsigned short* __restrict__ A,
    const unsigned short* __restrict__ Bt,
    const float* __restrict__ a_s,
    const float* __restrict__ bias0,
    const float* __restrict__ bias1,
    unsigned short* __restrict__ u_out,
    unsigned short* __restrict__ dx_buf,
    float* __restrict__ out)
{
  __shared__ __align__(16) unsigned char smem[32768];
  unsigned short* lA = (unsigned short*)smem;            // 128 x 64 bf16
  unsigned short* lB = (unsigned short*)(smem + 16384);  // 128 x 64 bf16
  float* stg = (float*)smem;                             // epilogue stage, 32 x 132 fp32

  const int tid = threadIdx.x;
  const int flat = blockIdx.y * gridDim.x + blockIdx.x;
  const int xcd = flat & 7;
  const int j = flat >> 3;
  const int n0 = (j % NB) * 128;
  const int m0 = ((j / NB) * 8 + xcd) * 128;

  const int wid = tid >> 6, lane = tid & 63;
  const int wm = (wid >> 1) * 64, wn = (wid & 1) * 64;
  const int r16 = lane & 15, quad = lane >> 4;
  const int sw = r16 & 7;

  const int rsub = lane >> 3;
  const int gcol = ((lane & 7) ^ rsub) << 3;

  const unsigned short* Abase = A + (size_t)(m0 + (wid << 5) + rsub) * K + gcol;
  const unsigned short* Bbase = Bt + (size_t)(n0 + (wid << 5) + rsub) * K + gcol;
  unsigned short* lAw = lA + (wid << 5) * 64;
  unsigned short* lBw = lB + (wid << 5) * 64;

  floatx4 acc[4][4] = {};

  for (int k0 = 0; k0 < K; k0 += 64) {
#pragma unroll
    for (int i = 0; i < 4; ++i) {
      gl_lds16(Abase + (size_t)(i * 8) * K + k0, lAw + i * 8 * 64);
      gl_lds16(Bbase + (size_t)(i * 8) * K + k0, lBw + i * 8 * 64);
    }
    __syncthreads();
#pragma unroll
    for (int ks = 0; ks < 2; ++ks) {
      bf16x8 af[4], bfr[4];
#pragma unroll
      for (int i = 0; i < 4; ++i)
        af[i] = *(const bf16x8*)&lA[(wm + i * 16 + r16) * 64 + ((((ks << 2) | quad) ^ sw) << 3)];
#pragma unroll
      for (int j2 = 0; j2 < 4; ++j2)
        bfr[j2] = *(const bf16x8*)&lB[(wn + j2 * 16 + r16) * 64 + ((((ks << 2) | quad) ^ sw) << 3)];
#pragma unroll
      for (int i = 0; i < 4; ++i)
#pragma unroll
        for (int j2 = 0; j2 < 4; ++j2)
          acc[i][j2] = __builtin_amdgcn_mfma_f32_16x16x32_bf16(af[i], bfr[j2], acc[i][j2], 0, 0, 0);
    }
    __syncthreads();
  }

  // ---- epilogue: 4 passes of 32 rows through LDS (fp32, stride 132), coalesced stores ----
  const int row = tid >> 3;   // 0..31
  const int seg = tid & 7;    // 0..7
#pragma unroll
  for (int p = 0; p < 4; ++p) {
    __syncthreads();
    if ((wid >> 1) == (p >> 1)) {
      const int i0 = (p & 1) * 2;
#pragma unroll
      for (int ii = 0; ii < 2; ++ii) {
        const int i = i0 + ii;
        const int srow = i * 16 + quad * 4 - (p & 1) * 32;
#pragma unroll
        for (int j2 = 0; j2 < 4; ++j2) {
          const int scol = wn + j2 * 16 + r16;
#pragma unroll
          for (int r = 0; r < 4; ++r)
            stg[(srow + r) * 132 + scol] = acc[i][j2][r];
        }
      }
    }
    __syncthreads();
    const int gm = m0 + p * 32 + row;
    const int col0 = n0 + seg * 16;
    if (MODE == 0) {
      union { unsigned short s[16]; uint4 q[2]; } ub;
      if (n0 < DHID) {
#pragma unroll
        for (int u = 0; u < 4; ++u) {
          float4 v  = *(const float4*)&stg[row * 132 + seg * 16 + u * 4];
          float4 bi = *(const float4*)&bias0[col0 + u * 4];
          float4 sc = *(const float4*)&a_s[DHID + col0 + u * 4];
          ub.s[u * 4 + 0] = f2bf((v.x + bi.x) * sc.x);
          ub.s[u * 4 + 1] = f2bf((v.y + bi.y) * sc.y);
          ub.s[u * 4 + 2] = f2bf((v.z + bi.z) * sc.z);
          ub.s[u * 4 + 3] = f2bf((v.w + bi.w) * sc.w);
        }
        *(uint4*)&u_out[(size_t)gm * DHID + col0]     = ub.q[0];
        *(uint4*)&u_out[(size_t)gm * DHID + col0 + 8] = ub.q[1];
      } else {
        const int c2 = col0 - DHID;
#pragma unroll
        for (int u = 0; u < 4; ++u) {
          float4 v  = *(const float4*)&stg[row * 132 + seg * 16 + u * 4];
          float4 bd = *(const float4*)&bias1[c2 + u * 4];
          ub.s[u * 4 + 0] = f2bf(v.x + bd.x);
          ub.s[u * 4 + 1] = f2bf(v.y + bd.y);
          ub.s[u * 4 + 2] = f2bf(v.z + bd.z);
          ub.s[u * 4 + 3] = f2bf(v.w + bd.w);
        }
        *(uint4*)&dx_buf[(size_t)gm * DOUT + c2]     = ub.q[0];
        *(uint4*)&dx_buf[(size_t)gm * DOUT + c2 + 8] = ub.q[1];
      }
    } else {
#pragma unroll
      for (int u = 0; u < 4; ++u) {
        float4 v  = *(const float4*)&stg[row * 132 + seg * 16 + u * 4];
        float4 bo = *(const float4*)&bias0[col0 + u * 4];
        ushort4 dv = *(const ushort4*)&dx_buf[(size_t)gm * DOUT + col0 + u * 4];
        float4 o;
        o.x = (v.x + bo.x + bf2f(dv.x)) * 0.5f;
        o.y = (v.y + bo.y + bf2f(dv.y)) * 0.5f;
        o.z = (v.z + bo.z + bf2f(dv.z)) * 0.5f;
        o.w = (v.w + bo.w + bf2f(dv.w)) * 0.5f;
        *(float4*)&out[(size_t)gm * DOUT + col0 + u * 4] = o;
      }
    }
  }
}

// ---------- scan kernels: 8 d's per thread, 16 B/lane fully-coalesced ----------
__global__ __launch_bounds__(256) void scan1(const unsigned short* __restrict__ u,
                                             const float* __restrict__ a_s,
                                             float* __restrict__ carry) {
  int idx = blockIdx.x * 256 + threadIdx.x;       // B*NCH2*(DHID/8) = 131072
  int d8 = (idx & 127) * 8;
  int c  = (idx >> 7) & (NCH2 - 1);
  int b  = idx >> 14;
  float4 a0 = *(const float4*)&a_s[d8];
  float4 a1 = *(const float4*)&a_s[d8 + 4];
  float h0_ = 0.f, h1 = 0.f, h2 = 0.f, h3 = 0.f, h4 = 0.f, h5 = 0.f, h6 = 0.f, h7 = 0.f;
  const unsigned short* up = u + ((size_t)(b * S_ + c * CH2)) * DHID + d8;
#pragma unroll 4
  for (int t = 0; t < CH2; ++t) {
    ushort4 q0 = *(const ushort4*)up;
    ushort4 q1 = *(const ushort4*)(up + 4);
    h0_ = fmaf(a0.x, h0_, bf2f(q0.x)); h1 = fmaf(a0.y, h1, bf2f(q0.y));
    h2  = fmaf(a0.z, h2,  bf2f(q0.z)); h3 = fmaf(a0.w, h3, bf2f(q0.w));
    h4  = fmaf(a1.x, h4,  bf2f(q1.x)); h5 = fmaf(a1.y, h5, bf2f(q1.y));
    h6  = fmaf(a1.z, h6,  bf2f(q1.z)); h7 = fmaf(a1.w, h7, bf2f(q1.w));
    up += DHID;
  }
  float* cp = &carry[((size_t)(b * NCH2 + c)) * DHID + d8];
  float4 o0 = {h0_, h1, h2, h3}, o1 = {h4, h5, h6, h7};
  *(float4*)cp = o0;
  *(float4*)(cp + 4) = o1;
}

// pass 1.5: sequential prefix over chunks with 8-deep load batching to pipeline
// the serial-chain latency. carry becomes exact chunk-entry state; writes h_last.
__global__ __launch_bounds__(256) void scan_mid(const float* __restrict__ a_s,
                                                const float* __restrict__ h0,
                                                float* __restrict__ carry,
                                                float* __restrict__ h_last) {
  int idx = blockIdx.x * 256 + threadIdx.x;   // B_*DHID = 8192
  int d = idx & (DHID - 1);
  int b = idx >> 10;
  float a = a_s[d];
  float aL = a;
#pragma unroll
  for (int q = 0; q < 5; ++q) aL *= aL;       // a^32
  float st = h0[(size_t)b * DHID + d];
  float* p = &carry[(size_t)b * NCH2 * DHID + d];
  for (int cg = 0; cg < NCH2; cg += 8) {
    float loc[8];
#pragma unroll
    for (int j = 0; j < 8; ++j) loc[j] = p[(size_t)j * DHID];   // 8 independent loads in flight
#pragma unroll
    for (int j = 0; j < 8; ++j) {
      p[(size_t)j * DHID] = st;
      st = fmaf(aL, st, loc[j]);
    }
    p += (size_t)8 * DHID;
  }
  h_last[(size_t)b * DHID + d] = st;
}

// pass 2: recompute scan from exact entry state; overwrite u with h (bf16)
__global__ __launch_bounds__(256) void scan2(unsigned short* __restrict__ u,
                                             const float* __restrict__ a_s,
                                             const float* __restrict__ carry) {
  int idx = blockIdx.x * 256 + threadIdx.x;
  int d8 = (idx & 127) * 8;
  int c  = (idx >> 7) & (NCH2 - 1);
  int b  = idx >> 14;
  float4 a0 = *(const float4*)&a_s[d8];
  float4 a1 = *(const float4*)&a_s[d8 + 4];
  const float* cp = &carry[((size_t)(b * NCH2 + c)) * DHID + d8];
  float4 e0 = *(const float4*)cp;
  float4 e1 = *(const float4*)(cp + 4);
  float h0_ = e0.x, h1 = e0.y, h2 = e0.z, h3 = e0.w;
  float h4 = e1.x, h5 = e1.y, h6 = e1.z, h7 = e1.w;
  unsigned short* up = u + ((size_t)(b * S_ + c * CH2)) * DHID + d8;
#pragma unroll 4
  for (int t = 0; t < CH2; ++t) {
    ushort4 q0 = *(const ushort4*)up;
    ushort4 q1 = *(const ushort4*)(up + 4);
    h0_ = fmaf(a0.x, h0_, bf2f(q0.x)); h1 = fmaf(a0.y, h1, bf2f(q0.y));
    h2  = fmaf(a0.z, h2,  bf2f(q0.z)); h3 = fmaf(a0.w, h3, bf2f(q0.w));
    h4  = fmaf(a1.x, h4,  bf2f(q1.x)); h5 = fmaf(a1.y, h5, bf2f(q1.y));
    h6  = fmaf(a1.z, h6,  bf2f(q1.z)); h7 = fmaf(a1.w, h7, bf2f(q1.w));
    ushort4 w0, w1;
    w0.x = f2bf(h0_); w0.y = f2bf(h1); w0.z = f2bf(h2); w0.w = f2bf(h3);
    w1.x = f2bf(h4);  w1.y = f2bf(h5); w1.z = f2bf(h6); w1.w = f2bf(h7);
    *(ushort4*)up = w0;
    *(ushort4*)(up + 4) = w1;
    up += DHID;
  }
}

extern "C" void kernel_launch(void* const* d_in, const int* in_sizes, int n_in,
                              void* d_out, int out_size, void* d_ws, size_t ws_size,
                              hipStream_t stream) {
  const float* x    = (const float*)d_in[0];
  const float* h0   = (const float*)d_in[1];
  const float* alog = (const float*)d_in[2];
  const float* Wdx  = (const float*)d_in[3];
  const float* bdx  = (const float*)d_in[4];
  const float* Win  = (const float*)d_in[5];
  const float* bin  = (const float*)d_in[6];
  const float* Wout = (const float*)d_in[7];
  const float* bout = (const float*)d_in[8];

  float* out    = (float*)d_out;
  float* h_last = out + (size_t)M_ * DOUT;

  char* ws = (char*)d_ws;
  unsigned short* xb    = (unsigned short*)(ws);                      // 32 MB (dead after GEMM1)
  unsigned short* ubuf  = (unsigned short*)(ws + 33554432ull);        // 64 MB (u -> h in-place)
  unsigned short* dxb   = (unsigned short*)(ws + 100663296ull);       // 32 MB
  unsigned short* wcat  = (unsigned short*)(ws + 134217728ull);       // 1.5 MB
  unsigned short* woutt = (unsigned short*)(ws + 135790592ull);       // 1 MB
  float*          a_s   = (float*)(ws + 136839168ull);                // 8 KB
  float*          carry = (float*)(ws);                               // 4 MB, aliases dead xb

  prep_as  <<<4, 256, 0, stream>>>(alog, a_s);
  prep_x   <<<(M_ * DIN / 8) / 256, 256, 0, stream>>>(x, xb);
  prep_wcat<<<(NCAT * DIN) / 256, 256, 0, stream>>>(Win, Wdx, wcat);
  prep_wout<<<(DOUT * DHID) / 256, 256, 0, stream>>>(Wout, woutt);

  // GEMM1: u = (x@W_in + b_in)*s (bf16), dx = x@W_dx + b_dx (bf16)
  gemm_bt<DIN, 0, 12><<<dim3(NCAT / 128, M_ / 128), 256, 0, stream>>>(
      xb, wcat, a_s, bin, bdx, ubuf, dxb, nullptr);

  // linear scan (chunked, CH2=32)
  scan1   <<<(B_ * NCH2 * (DHID / 8)) / 256, 256, 0, stream>>>(ubuf, a_s, carry);
  scan_mid<<<(B_ * DHID) / 256, 256, 0, stream>>>(a_s, h0, carry, h_last);
  scan2   <<<(B_ * NCH2 * (DHID / 8)) / 256, 256, 0, stream>>>(ubuf, a_s, carry);

  // GEMM2: out = (dx + h@W_out + b_out)/2
  gemm_bt<DHID, 1, 4><<<dim3(DOUT / 128, M_ / 128), 256, 0, stream>>>(
      ubuf, woutt, a_s, bout, nullptr, nullptr, dxb, out);
}